// Round 5
// baseline (45.934 us; speedup 1.0000x reference)
//
#include <hip/hip_runtime.h>
#include <hip/hip_bf16.h>

// out[b][c] = kxx_mean[b] + kyy[c] - 2*kxy_mean[b][c]
// x[32768][64] f32, atoms[64][32][64] f32, out[256][64] f32.
// Fused split-bf16 MFMA; exp forced to raw v_exp_f32 (HW exp2) via inline asm.

constexpr int   NODES = 128;
constexpr int   DD    = 64;
constexpr int   CC    = 64;
constexpr int   KK    = 32;
constexpr float GAMMA = 1.0f / 64.0f;
constexpr float LOG2E = 1.4426950408889634f;
constexpr float C1    = 2.0f * GAMMA * LOG2E;   // exp2-domain scale on S
constexpr float GL    = GAMMA * LOG2E;

typedef __attribute__((ext_vector_type(8)))  short short8;
typedef __attribute__((ext_vector_type(16))) float f32x16;

#define MFMA(a, b, c) __builtin_amdgcn_mfma_f32_32x32x16_bf16((a), (b), (c), 0, 0, 0)

// Single-instruction HW exp2 (v_exp_f32 computes 2^x, ~1 ulp).
__device__ __forceinline__ float fexp2(float x) {
    float r;
    asm("v_exp_f32 %0, %1" : "=v"(r) : "v"(x));
    return r;
}

__device__ __forceinline__ unsigned short f2bf(float f) {
    union { float f; unsigned int u; } a; a.f = f;
    unsigned int u = a.u;
    return (unsigned short)((u + 0x7FFFu + ((u >> 16) & 1u)) >> 16);  // RNE
}
__device__ __forceinline__ float bf2f(unsigned short b) {
    union { unsigned int u; float f; } a; a.u = ((unsigned int)b) << 16;
    return a.f;
}

// ---------------------------------------------------------------------------
// prep_atoms: atoms -> B-frag stream (hi/lo) + eck + kyy. (validated r2-r4)
// B entry: lane l holds col (l&31), k = kt*16+(l>>5)*8+j.
// index: (c*8 + kt*2 + h)*64 + l
// ---------------------------------------------------------------------------
__global__ __launch_bounds__(256) void prep_atoms(const float* __restrict__ atoms,
                                                  short8* __restrict__ bfrag,
                                                  float* __restrict__ eck,
                                                  float* __restrict__ kyy) {
    const int c = blockIdx.x, t = threadIdx.x;
    __shared__ float a[KK][DD + 1];
    __shared__ float an[KK];
    __shared__ float wred[4];

    const float* ac = atoms + (size_t)c * KK * DD;
    for (int i = t; i < KK * DD; i += 256) a[i >> 6][i & 63] = ac[i];
    __syncthreads();

    if (t < KK) {
        float s = 0.f;
#pragma unroll
        for (int d = 0; d < DD; ++d) s = fmaf(a[t][d], a[t][d], s);
        an[t] = s;
        eck[c * KK + t] = fexp2(-GL * s);
    }
    __syncthreads();

    {   // fragment emit: wave w handles ktile w
        const int w = t >> 6, l = t & 63;
        const int kp = l & 31, kh = l >> 5;
        short8 hi, lo;
#pragma unroll
        for (int j = 0; j < 8; ++j) {
            const float f  = a[kp][w * 16 + kh * 8 + j];
            const unsigned short hb = f2bf(f);
            hi[j] = (short)hb;
            lo[j] = (short)f2bf(f - bf2f(hb));
        }
        const size_t idx = ((size_t)c * 8 + w * 2) * 64 + l;
        bfrag[idx]      = hi;
        bfrag[idx + 64] = lo;
    }

    {   // kyy
        const int i = t >> 3, j0 = (t & 7) * 4;
        float s0 = 0, s1 = 0, s2 = 0, s3 = 0;
        for (int d = 0; d < DD; ++d) {
            const float aid = a[i][d];
            s0 = fmaf(aid, a[j0 + 0][d], s0);
            s1 = fmaf(aid, a[j0 + 1][d], s1);
            s2 = fmaf(aid, a[j0 + 2][d], s2);
            s3 = fmaf(aid, a[j0 + 3][d], s3);
        }
        const float ani = an[i];
        float s = fexp2(-GL * (ani + an[j0 + 0] - 2.f * s0))
                + fexp2(-GL * (ani + an[j0 + 1] - 2.f * s1))
                + fexp2(-GL * (ani + an[j0 + 2] - 2.f * s2))
                + fexp2(-GL * (ani + an[j0 + 3] - 2.f * s3));
#pragma unroll
        for (int off = 32; off; off >>= 1) s += __shfl_xor(s, off);
        if ((t & 63) == 0) wred[t >> 6] = s;
    }
    __syncthreads();
    if (t == 0) kyy[c] = (wred[0] + wred[1] + wred[2] + wred[3]) * (1.0f / (KK * KK));
}

// ---------------------------------------------------------------------------
// mmd_fused: grid 1024 = (b, cq), block 256 = 4 waves (wave = rowtile).
// it=0: kxx tile (B = x-frags of rowtile cq); it=1..16: atoms cq*16+it-1.
// ---------------------------------------------------------------------------
__global__ __launch_bounds__(256, 3) void mmd_fused(const float* __restrict__ x,
                                                    const short8* __restrict__ bfrag,
                                                    const float* __restrict__ eck,
                                                    float* __restrict__ kxxp,
                                                    float* __restrict__ sxyw) {
    const int bid = blockIdx.x;
    const int b = bid >> 2, cq = bid & 3;
    const int t = threadIdx.x, w = t >> 6, l = t & 63;
    const int l31 = l & 31, kh = l >> 5;

    __shared__ short8 Bb[2][512];          // 16 KB double buffer
    __shared__ float  part[4][17][64];     // per-lane partials
    __shared__ float  norm_lds[NODES];
    __shared__ float  ec_lds[16][KK];

    // ---- A fragments (rowtile w) from x, in registers ----
    float v[32];
    {
        const float* xr = x + ((size_t)(b * NODES + w * 32 + l31)) * DD + kh * 8;
#pragma unroll
        for (int kt = 0; kt < 4; ++kt) {
            const float4 p0 = *reinterpret_cast<const float4*>(xr + kt * 16);
            const float4 p1 = *reinterpret_cast<const float4*>(xr + kt * 16 + 4);
            v[kt*8+0]=p0.x; v[kt*8+1]=p0.y; v[kt*8+2]=p0.z; v[kt*8+3]=p0.w;
            v[kt*8+4]=p1.x; v[kt*8+5]=p1.y; v[kt*8+6]=p1.z; v[kt*8+7]=p1.w;
        }
    }
    float xn = 0.f;
#pragma unroll
    for (int i = 0; i < 32; ++i) xn = fmaf(v[i], v[i], xn);
    xn += __shfl_xor(xn, 32);
    if (l < 32) norm_lds[w * 32 + l] = xn;

    short8 A[4][2];
#pragma unroll
    for (int kt = 0; kt < 4; ++kt) {
        short8 hi, lo;
#pragma unroll
        for (int j = 0; j < 8; ++j) {
            const float f = v[kt * 8 + j];
            const unsigned short hb = f2bf(f);
            hi[j] = (short)hb;
            lo[j] = (short)f2bf(f - bf2f(hb));
        }
        A[kt][0] = hi; A[kt][1] = lo;
    }

    // ---- stage Bx (x-frags of rowtile cq) into Bb[0]; ec table; prefetch atom0 ----
    for (int e = t; e < 512; e += 256) {
        const int kt = e >> 7, h = (e >> 6) & 1, ll = e & 63;
        const float* p = x + ((size_t)(b * NODES + cq * 32 + (ll & 31))) * DD
                         + kt * 16 + ((ll >> 5) * 8);
        const float4 q0 = *reinterpret_cast<const float4*>(p);
        const float4 q1 = *reinterpret_cast<const float4*>(p + 4);
        const float vv[8] = {q0.x, q0.y, q0.z, q0.w, q1.x, q1.y, q1.z, q1.w};
        short8 f;
#pragma unroll
        for (int j = 0; j < 8; ++j) {
            const unsigned short hb = f2bf(vv[j]);
            f[j] = (h == 0) ? (short)hb : (short)f2bf(vv[j] - bf2f(hb));
        }
        Bb[0][e] = f;
    }
    for (int i = t; i < 512; i += 256) ec_lds[i >> 5][i & 31] = eck[cq * 512 + i];

    const short8* bq = bfrag + (size_t)(cq * 16) * 512;
    short8 r0 = bq[t];
    short8 r1 = bq[256 + t];

    __syncthreads();   // norms, Bb[0], ec_lds ready

    float cxv[16];
#pragma unroll
    for (int r = 0; r < 16; ++r) {
        const int ro = (r & 3) + 8 * (r >> 2) + 4 * kh;
        cxv[r] = -GL * norm_lds[w * 32 + ro];
    }
    const float ec0 = fexp2(-GL * norm_lds[cq * 32 + l31]);

    // ---- 17-iteration main loop ----
    for (int it = 0; it <= 16; ++it) {
        const int buf = it & 1;
        __syncthreads();

        short8 B[4][2];
#pragma unroll
        for (int kt = 0; kt < 4; ++kt)
#pragma unroll
            for (int h = 0; h < 2; ++h)
                B[kt][h] = Bb[buf][(kt * 2 + h) * 64 + l];

        if (it < 16) {   // write next tile from regs, then issue prefetch
            Bb[buf ^ 1][t]       = r0;
            Bb[buf ^ 1][t + 256] = r1;
            if (it < 15) {
                r0 = bq[(it + 1) * 512 + t];
                r1 = bq[(it + 1) * 512 + 256 + t];
            }
        }
        const float ec = (it == 0) ? ec0 : ec_lds[it - 1][l31];

        f32x16 acc0 = {}, acc1 = {};
        acc0 = MFMA(A[0][0], B[0][0], acc0);  acc1 = MFMA(A[2][0], B[2][0], acc1);
        acc0 = MFMA(A[0][0], B[0][1], acc0);  acc1 = MFMA(A[2][0], B[2][1], acc1);
        acc0 = MFMA(A[0][1], B[0][0], acc0);  acc1 = MFMA(A[2][1], B[2][0], acc1);
        acc0 = MFMA(A[1][0], B[1][0], acc0);  acc1 = MFMA(A[3][0], B[3][0], acc1);
        acc0 = MFMA(A[1][0], B[1][1], acc0);  acc1 = MFMA(A[3][0], B[3][1], acc1);
        acc0 = MFMA(A[1][1], B[1][0], acc0);  acc1 = MFMA(A[3][1], B[3][0], acc1);

        float sa = 0.f, sb = 0.f;
#pragma unroll
        for (int r = 0; r < 16; r += 2) {
            sa += fexp2(fmaf(C1, acc0[r]     + acc1[r],     cxv[r]));
            sb += fexp2(fmaf(C1, acc0[r + 1] + acc1[r + 1], cxv[r + 1]));
        }
        part[w][it][l] = (sa + sb) * ec;
    }

    __syncthreads();
    // ---- block reduce: part[4][17][64] -> 17 scalars ----
    for (int ci = t >> 4; ci < 17; ci += 16) {
        const int g = t & 15;
        float s = 0.f;
#pragma unroll
        for (int ww = 0; ww < 4; ++ww)
#pragma unroll
            for (int j = 0; j < 4; ++j) s += part[ww][ci][g + 16 * j];
        s += __shfl_xor(s, 1);
        s += __shfl_xor(s, 2);
        s += __shfl_xor(s, 4);
        s += __shfl_xor(s, 8);
        if (g == 0) {
            if (ci == 0) kxxp[b * 4 + cq] = s;
            else         sxyw[b * CC + cq * 16 + (ci - 1)] = s;
        }
    }
}

// ---------------------------------------------------------------------------
// combine: out[b][c] = sum(kxxp[b])/16384 + kyy[c] - sxyw[b][c]/2048
// ---------------------------------------------------------------------------
__global__ __launch_bounds__(256) void combine(const float* __restrict__ kxxp,
                                               const float* __restrict__ kyy,
                                               const float* __restrict__ sxyw,
                                               float* __restrict__ out) {
    const int idx = blockIdx.x * 256 + threadIdx.x;
    const int b = idx >> 6, c = idx & 63;
    const float kxx = (kxxp[b * 4 + 0] + kxxp[b * 4 + 1] +
                       kxxp[b * 4 + 2] + kxxp[b * 4 + 3]) * (1.0f / 16384.0f);
    out[idx] = kxx + kyy[c] - sxyw[idx] * (1.0f / 2048.0f);
}

extern "C" void kernel_launch(void* const* d_in, const int* in_sizes, int n_in,
                              void* d_out, int out_size, void* d_ws, size_t ws_size,
                              hipStream_t stream) {
    const float* x     = (const float*)d_in[0];   // [32768, 64]
    const float* atoms = (const float*)d_in[1];   // [64, 32, 64]
    float* out = (float*)d_out;                   // [256, 64]

    char* ws = (char*)d_ws;
    short8* bfrag = (short8*)ws;                          // 512 KiB
    float*  eck   = (float*)(ws + 524288);                // 8 KiB
    float*  kyy   = (float*)(ws + 532480);                // 256 B
    float*  kxxp  = (float*)(ws + 532736);                // 4 KiB
    float*  sxyw  = (float*)(ws + 536832);                // 64 KiB

    prep_atoms<<<dim3(CC),   dim3(256), 0, stream>>>(atoms, bfrag, eck, kyy);
    mmd_fused <<<dim3(1024), dim3(256), 0, stream>>>(x, bfrag, eck, kxxp, sxyw);
    combine   <<<dim3(CC),   dim3(256), 0, stream>>>(kxxp, kyy, sxyw, out);
}

// Round 6
// 43.466 us; speedup vs baseline: 1.0568x; 1.0568x over previous
//
#include <hip/hip_runtime.h>
#include <hip/hip_bf16.h>

// out[b][c] = kxx_mean[b] + kyy[c] - 2*kxy_mean[b][c]
// x[32768][64] f32, atoms[64][32][64] f32, out[256][64] f32.
// Fused split-bf16 MFMA. R6: LDS 36KB->15KB (single-buffer B, 16-lane part),
// single acc chain, reg cap 128 for 4 waves/SIMD.

constexpr int   NODES = 128;
constexpr int   DD    = 64;
constexpr int   CC    = 64;
constexpr int   KK    = 32;
constexpr float GAMMA = 1.0f / 64.0f;
constexpr float LOG2E = 1.4426950408889634f;
constexpr float C1    = 2.0f * GAMMA * LOG2E;   // exp2-domain scale on S
constexpr float GL    = GAMMA * LOG2E;

typedef __attribute__((ext_vector_type(8)))  short short8;
typedef __attribute__((ext_vector_type(16))) float f32x16;

#define MFMA(a, b, c) __builtin_amdgcn_mfma_f32_32x32x16_bf16((a), (b), (c), 0, 0, 0)

__device__ __forceinline__ float fexp2(float x) {
    float r;
    asm("v_exp_f32 %0, %1" : "=v"(r) : "v"(x));
    return r;
}

__device__ __forceinline__ unsigned short f2bf(float f) {
    union { float f; unsigned int u; } a; a.f = f;
    unsigned int u = a.u;
    return (unsigned short)((u + 0x7FFFu + ((u >> 16) & 1u)) >> 16);  // RNE
}
__device__ __forceinline__ float bf2f(unsigned short b) {
    union { unsigned int u; float f; } a; a.u = ((unsigned int)b) << 16;
    return a.f;
}

// ---------------------------------------------------------------------------
// prep_atoms: atoms -> B-frag stream (hi/lo) + eck + kyy. (validated r2-r5)
// B entry: lane l holds col (l&31), k = kt*16+(l>>5)*8+j.
// index: (c*8 + kt*2 + h)*64 + l
// ---------------------------------------------------------------------------
__global__ __launch_bounds__(256) void prep_atoms(const float* __restrict__ atoms,
                                                  short8* __restrict__ bfrag,
                                                  float* __restrict__ eck,
                                                  float* __restrict__ kyy) {
    const int c = blockIdx.x, t = threadIdx.x;
    __shared__ float a[KK][DD + 1];
    __shared__ float an[KK];
    __shared__ float wred[4];

    const float* ac = atoms + (size_t)c * KK * DD;
    for (int i = t; i < KK * DD; i += 256) a[i >> 6][i & 63] = ac[i];
    __syncthreads();

    if (t < KK) {
        float s = 0.f;
#pragma unroll
        for (int d = 0; d < DD; ++d) s = fmaf(a[t][d], a[t][d], s);
        an[t] = s;
        eck[c * KK + t] = fexp2(-GL * s);
    }
    __syncthreads();

    {   // fragment emit: wave w handles ktile w
        const int w = t >> 6, l = t & 63;
        const int kp = l & 31, kh = l >> 5;
        short8 hi, lo;
#pragma unroll
        for (int j = 0; j < 8; ++j) {
            const float f  = a[kp][w * 16 + kh * 8 + j];
            const unsigned short hb = f2bf(f);
            hi[j] = (short)hb;
            lo[j] = (short)f2bf(f - bf2f(hb));
        }
        const size_t idx = ((size_t)c * 8 + w * 2) * 64 + l;
        bfrag[idx]      = hi;
        bfrag[idx + 64] = lo;
    }

    {   // kyy
        const int i = t >> 3, j0 = (t & 7) * 4;
        float s0 = 0, s1 = 0, s2 = 0, s3 = 0;
        for (int d = 0; d < DD; ++d) {
            const float aid = a[i][d];
            s0 = fmaf(aid, a[j0 + 0][d], s0);
            s1 = fmaf(aid, a[j0 + 1][d], s1);
            s2 = fmaf(aid, a[j0 + 2][d], s2);
            s3 = fmaf(aid, a[j0 + 3][d], s3);
        }
        const float ani = an[i];
        float s = fexp2(-GL * (ani + an[j0 + 0] - 2.f * s0))
                + fexp2(-GL * (ani + an[j0 + 1] - 2.f * s1))
                + fexp2(-GL * (ani + an[j0 + 2] - 2.f * s2))
                + fexp2(-GL * (ani + an[j0 + 3] - 2.f * s3));
#pragma unroll
        for (int off = 32; off; off >>= 1) s += __shfl_xor(s, off);
        if ((t & 63) == 0) wred[t >> 6] = s;
    }
    __syncthreads();
    if (t == 0) kyy[c] = (wred[0] + wred[1] + wred[2] + wred[3]) * (1.0f / (KK * KK));
}

// ---------------------------------------------------------------------------
// mmd_fused: grid 1024 = (b, cq), block 256 = 4 waves (wave = rowtile).
// it=0: kxx tile (B = x-frags of rowtile cq); it=1..16: atoms cq*16+it-1.
// Single-buffer Bb: read -> barrier -> write-next (hidden under compute) ->
// compute -> barrier. Per-iter partial pre-reduced to 16 lanes -> part16.
// ---------------------------------------------------------------------------
__global__ __launch_bounds__(256, 4) void mmd_fused(const float* __restrict__ x,
                                                    const short8* __restrict__ bfrag,
                                                    const float* __restrict__ eck,
                                                    float* __restrict__ kxxp,
                                                    float* __restrict__ sxyw) {
    const int bid = blockIdx.x;
    const int b = bid >> 2, cq = bid & 3;
    const int t = threadIdx.x, w = t >> 6, l = t & 63;
    const int l31 = l & 31, kh = l >> 5;

    __shared__ short8 Bb[512];            // 8 KB single buffer (one 32x64 tile)
    __shared__ float  part16[4][17][16];  // 4.25 KB pre-reduced partials
    __shared__ float  norm_lds[NODES];    // 512 B
    __shared__ float  ec_lds[16][KK];     // 2 KB

    // ---- A fragments (rowtile w) from x, in registers ----
    float v[32];
    {
        const float* xr = x + ((size_t)(b * NODES + w * 32 + l31)) * DD + kh * 8;
#pragma unroll
        for (int kt = 0; kt < 4; ++kt) {
            const float4 p0 = *reinterpret_cast<const float4*>(xr + kt * 16);
            const float4 p1 = *reinterpret_cast<const float4*>(xr + kt * 16 + 4);
            v[kt*8+0]=p0.x; v[kt*8+1]=p0.y; v[kt*8+2]=p0.z; v[kt*8+3]=p0.w;
            v[kt*8+4]=p1.x; v[kt*8+5]=p1.y; v[kt*8+6]=p1.z; v[kt*8+7]=p1.w;
        }
    }
    float xn = 0.f;
#pragma unroll
    for (int i = 0; i < 32; ++i) xn = fmaf(v[i], v[i], xn);
    xn += __shfl_xor(xn, 32);
    if (l < 32) norm_lds[w * 32 + l] = xn;

    short8 A[4][2];
#pragma unroll
    for (int kt = 0; kt < 4; ++kt) {
        short8 hi, lo;
#pragma unroll
        for (int j = 0; j < 8; ++j) {
            const float f = v[kt * 8 + j];
            const unsigned short hb = f2bf(f);
            hi[j] = (short)hb;
            lo[j] = (short)f2bf(f - bf2f(hb));
        }
        A[kt][0] = hi; A[kt][1] = lo;
    }

    // ---- stage Bx (x-frags of rowtile cq) into Bb; ec table; prefetch atom0 ----
    for (int e = t; e < 512; e += 256) {
        const int kt = e >> 7, h = (e >> 6) & 1, ll = e & 63;
        const float* p = x + ((size_t)(b * NODES + cq * 32 + (ll & 31))) * DD
                         + kt * 16 + ((ll >> 5) * 8);
        const float4 q0 = *reinterpret_cast<const float4*>(p);
        const float4 q1 = *reinterpret_cast<const float4*>(p + 4);
        const float vv[8] = {q0.x, q0.y, q0.z, q0.w, q1.x, q1.y, q1.z, q1.w};
        short8 f;
#pragma unroll
        for (int j = 0; j < 8; ++j) {
            const unsigned short hb = f2bf(vv[j]);
            f[j] = (h == 0) ? (short)hb : (short)f2bf(vv[j] - bf2f(hb));
        }
        Bb[e] = f;
    }
    for (int i = t; i < 512; i += 256) ec_lds[i >> 5][i & 31] = eck[cq * 512 + i];

    const short8* bq = bfrag + (size_t)(cq * 16) * 512;
    short8 r0 = bq[t];
    short8 r1 = bq[256 + t];

    __syncthreads();   // norms, Bb (it=0 tile), ec_lds ready

    float cxv[16];
#pragma unroll
    for (int r = 0; r < 16; ++r) {
        const int ro = (r & 3) + 8 * (r >> 2) + 4 * kh;
        cxv[r] = -GL * norm_lds[w * 32 + ro];
    }
    const float ec0 = fexp2(-GL * norm_lds[cq * 32 + l31]);

    // ---- 17-iteration main loop (2 barriers/iter, single LDS buffer) ----
    for (int it = 0; it <= 16; ++it) {
        short8 B[4][2];
#pragma unroll
        for (int kt = 0; kt < 4; ++kt)
#pragma unroll
            for (int h = 0; h < 2; ++h)
                B[kt][h] = Bb[(kt * 2 + h) * 64 + l];
        __syncthreads();               // all waves have read Bb

        if (it < 16) {                 // overwrite with next tile; hidden by compute
            Bb[t]       = r0;
            Bb[t + 256] = r1;
            if (it < 15) {
                r0 = bq[(it + 1) * 512 + t];
                r1 = bq[(it + 1) * 512 + 256 + t];
            }
        }
        const float ec = (it == 0) ? ec0 : ec_lds[it - 1][l31];

        f32x16 acc = {};
        acc = MFMA(A[0][0], B[0][0], acc);
        acc = MFMA(A[0][0], B[0][1], acc);
        acc = MFMA(A[0][1], B[0][0], acc);
        acc = MFMA(A[1][0], B[1][0], acc);
        acc = MFMA(A[1][0], B[1][1], acc);
        acc = MFMA(A[1][1], B[1][0], acc);
        acc = MFMA(A[2][0], B[2][0], acc);
        acc = MFMA(A[2][0], B[2][1], acc);
        acc = MFMA(A[2][1], B[2][0], acc);
        acc = MFMA(A[3][0], B[3][0], acc);
        acc = MFMA(A[3][0], B[3][1], acc);
        acc = MFMA(A[3][1], B[3][0], acc);

        float sa = 0.f, sb = 0.f;
#pragma unroll
        for (int r = 0; r < 16; r += 2) {
            sa += fexp2(fmaf(C1, acc[r],     cxv[r]));
            sb += fexp2(fmaf(C1, acc[r + 1], cxv[r + 1]));
        }
        float s = (sa + sb) * ec;
        s += __shfl_xor(s, 32);
        s += __shfl_xor(s, 16);
        if (l < 16) part16[w][it][l] = s;

        __syncthreads();               // next tile staged & visible
    }

    // ---- block reduce: part16[4][17][16] -> 17 scalars ----
    for (int ci = t >> 4; ci < 17; ci += 16) {
        const int g = t & 15;
        float s = part16[0][ci][g] + part16[1][ci][g]
                + part16[2][ci][g] + part16[3][ci][g];
        s += __shfl_xor(s, 8);
        s += __shfl_xor(s, 4);
        s += __shfl_xor(s, 2);
        s += __shfl_xor(s, 1);
        if (g == 0) {
            if (ci == 0) kxxp[b * 4 + cq] = s;
            else         sxyw[b * CC + cq * 16 + (ci - 1)] = s;
        }
    }
}

// ---------------------------------------------------------------------------
// combine: out[b][c] = sum(kxxp[b])/16384 + kyy[c] - sxyw[b][c]/2048
// ---------------------------------------------------------------------------
__global__ __launch_bounds__(256) void combine(const float* __restrict__ kxxp,
                                               const float* __restrict__ kyy,
                                               const float* __restrict__ sxyw,
                                               float* __restrict__ out) {
    const int idx = blockIdx.x * 256 + threadIdx.x;
    const int b = idx >> 6, c = idx & 63;
    const float kxx = (kxxp[b * 4 + 0] + kxxp[b * 4 + 1] +
                       kxxp[b * 4 + 2] + kxxp[b * 4 + 3]) * (1.0f / 16384.0f);
    out[idx] = kxx + kyy[c] - sxyw[idx] * (1.0f / 2048.0f);
}

extern "C" void kernel_launch(void* const* d_in, const int* in_sizes, int n_in,
                              void* d_out, int out_size, void* d_ws, size_t ws_size,
                              hipStream_t stream) {
    const float* x     = (const float*)d_in[0];   // [32768, 64]
    const float* atoms = (const float*)d_in[1];   // [64, 32, 64]
    float* out = (float*)d_out;                   // [256, 64]

    char* ws = (char*)d_ws;
    short8* bfrag = (short8*)ws;                          // 512 KiB
    float*  eck   = (float*)(ws + 524288);                // 8 KiB
    float*  kyy   = (float*)(ws + 532480);                // 256 B
    float*  kxxp  = (float*)(ws + 532736);                // 4 KiB
    float*  sxyw  = (float*)(ws + 536832);                // 64 KiB

    prep_atoms<<<dim3(CC),   dim3(256), 0, stream>>>(atoms, bfrag, eck, kyy);
    mmd_fused <<<dim3(1024), dim3(256), 0, stream>>>(x, bfrag, eck, kxxp, sxyw);
    combine   <<<dim3(CC),   dim3(256), 0, stream>>>(kxxp, kyy, sxyw, out);
}